// Round 1
// baseline (11.661 us; speedup 1.0000x reference)
//
#include <hip/hip_runtime.h>
#include <climits>

// Problem constants (match reference)
#define LROW 512
#define OUT_S 65
#define THRESH 0.2f
#define EPS_F 1e-6f

// One block per (n,c) row. 256 threads.
// Phase 1: find first/last nonzero index over 512 elems.
// Phase 2: masked sum -> mean (fp64 accumulate, fp32 result like reference).
// Phase 3: masked sum of (x-mean)^2 -> std.
// Phase 4: x_norm for first 65 elems into LDS.
// Phase 5: 65x65 recurrence plot, coalesced stores.
__global__ __launch_bounds__(256) void rp_kernel(const float* __restrict__ x,
                                                 float* __restrict__ out) {
    const int row = blockIdx.x;       // 0 .. N*C-1
    const int tid = threadIdx.x;      // 0 .. 255
    const float* xr = x + (size_t)row * LROW;

    __shared__ float  xs[LROW];
    __shared__ int    s_lo[256];
    __shared__ int    s_hi[256];
    __shared__ double s_d[256];
    __shared__ float  xn[OUT_S];

    // ---- load (each thread owns 2 elements) ----
    const float v0 = xr[tid];
    const float v1 = xr[tid + 256];
    xs[tid]       = v0;
    xs[tid + 256] = v1;

    // ---- phase 1: first/last nonzero ----
    int lo = INT_MAX, hi = -1;
    if (v0 != 0.0f) { lo = tid; hi = tid; }
    if (v1 != 0.0f) { lo = min(lo, tid + 256); hi = max(hi, tid + 256); }
    s_lo[tid] = lo;
    s_hi[tid] = hi;
    __syncthreads();
    for (int s = 128; s > 0; s >>= 1) {
        if (tid < s) {
            s_lo[tid] = min(s_lo[tid], s_lo[tid + s]);
            s_hi[tid] = max(s_hi[tid], s_hi[tid + s]);
        }
        __syncthreads();
    }
    const int  first = s_lo[0];
    const int  last  = s_hi[0];
    const bool anyNZ = (last >= 0);
    const float cnt  = anyNZ ? (float)(last - first + 1) : 1.0f;

    // ---- phase 2: masked mean ----
    double sum = 0.0;
    if (anyNZ) {
        if (tid >= first && tid <= last) sum += (double)v0;
        const int i1 = tid + 256;
        if (i1 >= first && i1 <= last) sum += (double)v1;
    }
    s_d[tid] = sum;
    __syncthreads();
    for (int s = 128; s > 0; s >>= 1) {
        if (tid < s) s_d[tid] += s_d[tid + s];
        __syncthreads();
    }
    const float mean = (float)(s_d[0] / (double)cnt);
    __syncthreads();  // all threads done reading s_d[0] before reuse

    // ---- phase 3: masked variance -> std ----
    double ss = 0.0;
    if (anyNZ) {
        if (tid >= first && tid <= last) {
            const float d = v0 - mean;           // fp32 subtract, like reference
            ss += (double)d * (double)d;
        }
        const int i1 = tid + 256;
        if (i1 >= first && i1 <= last) {
            const float d = v1 - mean;
            ss += (double)d * (double)d;
        }
    }
    s_d[tid] = ss;
    __syncthreads();
    for (int s = 128; s > 0; s >>= 1) {
        if (tid < s) s_d[tid] += s_d[tid + s];
        __syncthreads();
    }
    const float stdv = sqrtf((float)(s_d[0] / (double)cnt));
    const float stdc = fmaxf(stdv, EPS_F);       // clip(std, EPS)

    // ---- phase 4: x_norm for the first 65 positions ----
    if (tid < OUT_S) {
        const bool m = anyNZ && (tid >= first) && (tid <= last);
        xn[tid] = m ? (xs[tid] - mean) / stdc : 0.0f;   // fp32 divide, like reference
    }
    __syncthreads();

    // ---- phase 5: 65x65 recurrence plot ----
    float* orow = out + (size_t)row * (OUT_S * OUT_S);
    #pragma unroll 4
    for (int k = tid; k < OUT_S * OUT_S; k += 256) {
        const int i = k / OUT_S;
        const int j = k - i * OUT_S;
        orow[k] = (fabsf(xn[i] - xn[j]) < THRESH) ? 1.0f : 0.0f;
    }
}

extern "C" void kernel_launch(void* const* d_in, const int* in_sizes, int n_in,
                              void* d_out, int out_size, void* d_ws, size_t ws_size,
                              hipStream_t stream) {
    const float* x  = (const float*)d_in[0];
    float*      out = (float*)d_out;
    const int rows  = in_sizes[0] / LROW;   // 64*4 = 256
    rp_kernel<<<rows, 256, 0, stream>>>(x, out);
}

// Round 2
// 10.590 us; speedup vs baseline: 1.1011x; 1.1011x over previous
//
#include <hip/hip_runtime.h>
#include <climits>

// Problem constants (match reference)
#define LROW 512
#define OUT_S 65
#define NOUT (OUT_S * OUT_S)   // 4225
#define THRESH 0.2f
#define EPS_F 1e-6f

// One block per (n,c) row, 256 threads (4 waves).
// Key insight: elements outside [first_nz, last_nz] are zero by definition,
// so masked sum / sum-of-squares == full-row sum / sum-of-squares.
// -> single fused reduction of (lo, hi, S1, S2), wave-shuffle butterfly,
//    only 2 __syncthreads() total (was 26).
__global__ __launch_bounds__(256) void rp_kernel(const float* __restrict__ x,
                                                 float* __restrict__ out) {
    const int row = blockIdx.x;       // 0 .. N*C-1
    const int tid = threadIdx.x;      // 0 .. 255
    const float* xr = x + (size_t)row * LROW;

    // ---- load: each thread owns 2 elements ----
    const float v0 = xr[tid];
    const float v1 = xr[tid + 256];

    // ---- local stats ----
    int lo = INT_MAX, hi = -1;
    if (v0 != 0.0f) { lo = tid; hi = tid; }
    if (v1 != 0.0f) { lo = min(lo, tid + 256); hi = max(hi, tid + 256); }
    double s1 = (double)v0 + (double)v1;
    double s2 = (double)v0 * (double)v0 + (double)v1 * (double)v1;

    // ---- wave-level butterfly reduce (64 lanes, no barriers) ----
    #pragma unroll
    for (int off = 32; off > 0; off >>= 1) {
        lo = min(lo, __shfl_xor(lo, off, 64));
        hi = max(hi, __shfl_xor(hi, off, 64));
        s1 += __shfl_xor(s1, off, 64);
        s2 += __shfl_xor(s2, off, 64);
    }

    __shared__ int    w_lo[4], w_hi[4];
    __shared__ double w_s1[4], w_s2[4];
    __shared__ float  xn[OUT_S];

    const int wid = tid >> 6;
    if ((tid & 63) == 0) {
        w_lo[wid] = lo; w_hi[wid] = hi; w_s1[wid] = s1; w_s2[wid] = s2;
    }
    __syncthreads();   // barrier 1 of 2

    // ---- combine 4 wave partials (every thread, registers only) ----
    const int first = min(min(w_lo[0], w_lo[1]), min(w_lo[2], w_lo[3]));
    const int last  = max(max(w_hi[0], w_hi[1]), max(w_hi[2], w_hi[3]));
    const double S1 = (w_s1[0] + w_s1[1]) + (w_s1[2] + w_s1[3]);
    const double S2 = (w_s2[0] + w_s2[1]) + (w_s2[2] + w_s2[3]);

    const bool   anyNZ = (last >= 0);
    const double cnt   = anyNZ ? (double)(last - first + 1) : 1.0;
    const float  mean  = (float)(S1 / cnt);          // fp32 mean, like reference
    const double dm    = (double)mean;
    double var = (S2 - 2.0 * dm * S1 + cnt * dm * dm) / cnt;
    var = var > 0.0 ? var : 0.0;                     // guard tiny negative rounding
    const float stdc = fmaxf(sqrtf((float)var), EPS_F);

    // ---- x_norm for the first 65 positions (threads 0..64 own xr[tid]=v0) ----
    if (tid < OUT_S) {
        const bool m = anyNZ && (tid >= first) && (tid <= last);
        xn[tid] = m ? (v0 - mean) / stdc : 0.0f;     // fp32 divide, like reference
    }
    __syncthreads();   // barrier 2 of 2

    // ---- 65x65 recurrence plot, coalesced scalar stores ----
    float* orow = out + (size_t)row * NOUT;
    int k = tid;
    #pragma unroll
    for (int it = 0; it < 17; ++it) {
        if (k < NOUT) {
            const int ii = k / OUT_S;                // magic-mul division
            const int jj = k - ii * OUT_S;
            orow[k] = (fabsf(xn[ii] - xn[jj]) < THRESH) ? 1.0f : 0.0f;
        }
        k += 256;
    }
}

extern "C" void kernel_launch(void* const* d_in, const int* in_sizes, int n_in,
                              void* d_out, int out_size, void* d_ws, size_t ws_size,
                              hipStream_t stream) {
    const float* x  = (const float*)d_in[0];
    float*      out = (float*)d_out;
    const int rows  = in_sizes[0] / LROW;   // 64*4 = 256
    rp_kernel<<<rows, 256, 0, stream>>>(x, out);
}

// Round 3
// 9.773 us; speedup vs baseline: 1.1932x; 1.0836x over previous
//
#include <hip/hip_runtime.h>
#include <climits>

// Problem constants (match reference)
#define LROW 512
#define OUT_S 65
#define NOUT (OUT_S * OUT_S)   // 4225
#define THRESH 0.2f
#define EPS_F 1e-6f

typedef float f4 __attribute__((ext_vector_type(4)));

// One block per (n,c) row, 256 threads (4 waves), ZERO __syncthreads().
// Each wave redundantly loads the whole 2KB row (waves 1-3 L1-hit) and
// computes full-row stats with a private 6-step butterfly -> no cross-wave
// exchange. Each wave keeps a private xn[65] in LDS, ordered by a same-wave
// s_waitcnt. Output: 16B-aligned dwordx4 body + scalar head/tail
// (row base alignment cycles with row%4 since 4225 % 4 == 1).
__global__ __launch_bounds__(256) void rp_kernel(const float* __restrict__ x,
                                                 float* __restrict__ out) {
    const int row  = blockIdx.x;       // 0 .. N*C-1
    const int tid  = threadIdx.x;      // 0 .. 255
    const int lane = tid & 63;
    const int wid  = tid >> 6;
    const float* xr = x + (size_t)row * LROW;
    const f4* xr4   = reinterpret_cast<const f4*>(xr);   // row base is 2KB-aligned

    // ---- each wave loads the full row: 8 floats/lane (2x dwordx4) ----
    const f4 a = xr4[lane];        // x[4*lane .. 4*lane+3]
    const f4 b = xr4[lane + 64];   // x[256+4*lane .. 256+4*lane+3]

    // ---- local stats over 8 elements ----
    int lo = INT_MAX, hi = -1;
    double s1 = 0.0, s2 = 0.0;
    #pragma unroll
    for (int e = 0; e < 4; ++e) {
        const int   k0 = 4 * lane + e;
        const float va = a[e];
        if (va != 0.0f) { lo = min(lo, k0); hi = max(hi, k0); }
        s1 += (double)va; s2 += (double)va * (double)va;
        const int   k1 = k0 + 256;
        const float vb = b[e];
        if (vb != 0.0f) { lo = min(lo, k1); hi = max(hi, k1); }
        s1 += (double)vb; s2 += (double)vb * (double)vb;
    }

    // ---- wave butterfly (no barriers; identical result in every wave) ----
    #pragma unroll
    for (int off = 32; off > 0; off >>= 1) {
        lo = min(lo, __shfl_xor(lo, off, 64));
        hi = max(hi, __shfl_xor(hi, off, 64));
        s1 += __shfl_xor(s1, off, 64);
        s2 += __shfl_xor(s2, off, 64);
    }

    const bool   anyNZ = (hi >= 0);
    const double cnt   = anyNZ ? (double)(hi - lo + 1) : 1.0;
    const float  mean  = (float)(s1 / cnt);          // fp32 mean, like reference
    const double dm    = (double)mean;
    double var = (s2 - 2.0 * dm * s1 + cnt * dm * dm) / cnt;
    var = var > 0.0 ? var : 0.0;                     // guard tiny negative rounding
    const float stdc = fmaxf(sqrtf((float)var), EPS_F);

    // ---- per-wave private xn[65] (padded to 68): lanes 0..16 own x[0..67] ----
    __shared__ float xnw[4][68];                     // 272B/wave, 16B-aligned rows
    if (lane < 17) {
        f4 w;
        #pragma unroll
        for (int e = 0; e < 4; ++e) {
            const int  k = 4 * lane + e;
            const bool m = anyNZ && (k >= lo) && (k <= hi);
            w[e] = m ? (a[e] - mean) / stdc : 0.0f;  // fp32 ops, like reference
        }
        *reinterpret_cast<f4*>(&xnw[wid][4 * lane]) = w;
    }
    // same-wave LDS RAW: drain lgkm before any lane reads its wave's copy
    asm volatile("s_waitcnt lgkmcnt(0)" ::: "memory");

    const float* xn = xnw[wid];
    float* orow = out + (size_t)row * NOUT;

    // row base alignment: (row*4225*4) % 16 cycles; first 16B-aligned elem:
    const int h      = (4 - (row & 3)) & 3;          // head scalars (0..3)
    const int nbody  = (NOUT - h) >> 2;              // full float4 groups
    const int t0     = h + (nbody << 2);             // tail start
    const int ntail  = NOUT - t0;                    // tail scalars (0..3)

    if (tid < h) {                                   // head: k < 3 -> i=0, j=k
        orow[tid] = (fabsf(xn[0] - xn[tid]) < THRESH) ? 1.0f : 0.0f;
    }
    if (tid >= 4 && tid - 4 < ntail) {               // tail
        const int k = t0 + (tid - 4);
        const int i = k / OUT_S;
        const int j = k - i * OUT_S;
        orow[k] = (fabsf(xn[i] - xn[j]) < THRESH) ? 1.0f : 0.0f;
    }

    // body: aligned dwordx4 stores, <=5 iterations/thread
    for (int g = tid; g < nbody; g += 256) {
        const int e0 = h + 4 * g;
        const int i  = e0 / OUT_S;                   // magic-mul division
        int   jj  = e0 - i * OUT_S;
        float xii = xn[i];
        f4 r;
        #pragma unroll
        for (int e = 0; e < 4; ++e) {
            if (jj == OUT_S) { jj = 0; xii = xn[i + 1]; }  // row wrap (<=1 per group)
            r[e] = (fabsf(xii - xn[jj]) < THRESH) ? 1.0f : 0.0f;
            ++jj;
        }
        *reinterpret_cast<f4*>(orow + e0) = r;       // provably 16B-aligned
    }
}

extern "C" void kernel_launch(void* const* d_in, const int* in_sizes, int n_in,
                              void* d_out, int out_size, void* d_ws, size_t ws_size,
                              hipStream_t stream) {
    const float* x  = (const float*)d_in[0];
    float*      out = (float*)d_out;
    const int rows  = in_sizes[0] / LROW;   // 64*4 = 256
    rp_kernel<<<rows, 256, 0, stream>>>(x, out);
}